// Round 12
// baseline (819.964 us; speedup 1.0000x reference)
//
#include <hip/hip_runtime.h>
#include <math.h>

#define NB 16
#define PP 1024
#define DD 64
#define MAX_ITER 10
#define CH (NB * PP)           // partial-chunk stride (16384)

constexpr float EPSV    = 0.1f;
constexpr float SCALE_G = 20.0f;     // 2/eps
constexpr float LOG2E   = 1.44269504088896340736f;
constexpr float LOG_MU  = -6.93146156597137f;   // log(1/1024 + 1e-8)
constexpr float THRESHV = 0.1f;

typedef short bf16x8 __attribute__((ext_vector_type(8)));
typedef float f32x16 __attribute__((ext_vector_type(16)));

__device__ __forceinline__ unsigned short f2bf(float f) {
  unsigned int u = __float_as_uint(f);
  return (unsigned short)((u + 0x7FFFu + ((u >> 16) & 1u)) >> 16);   // RNE
}
__device__ __forceinline__ float bf2f(unsigned short h) {
  return __uint_as_float(((unsigned int)h) << 16);
}

// ---------------------------------------------------------------------------
// Prep (validated r8): bf16 hi/lo split + scaled row norms 10*|r|^2.
// ---------------------------------------------------------------------------
__global__ __launch_bounds__(256) void prep_kernel(
    const float* __restrict__ x, const float* __restrict__ y,
    unsigned short* __restrict__ xh, unsigned short* __restrict__ xl,
    unsigned short* __restrict__ yh, unsigned short* __restrict__ yl,
    float* __restrict__ nxs, float* __restrict__ nys)
{
  const int sel = blockIdx.x >> 9;
  const int row = (blockIdx.x & 511) * 32 + (threadIdx.x >> 3);
  const int q   = threadIdx.x & 7;

  const float* src = sel ? y : x;
  unsigned short* H = sel ? yh : xh;
  unsigned short* L = sel ? yl : xl;
  float* N          = sel ? nys : nxs;

  const float* p = src + (size_t)row * DD + q * 8;
  float4 v0 = *(const float4*)(p);
  float4 v1 = *(const float4*)(p + 4);

  float f[8] = {v0.x, v0.y, v0.z, v0.w, v1.x, v1.y, v1.z, v1.w};
  float nrm = 0.f;
  unsigned short hb[8], lb[8];
  #pragma unroll
  for (int k = 0; k < 8; ++k) {
    nrm = fmaf(f[k], f[k], nrm);
    unsigned short h = f2bf(f[k]);
    float res = f[k] - bf2f(h);
    hb[k] = h; lb[k] = f2bf(res);
  }
  nrm += __shfl_xor(nrm, 1);
  nrm += __shfl_xor(nrm, 2);
  nrm += __shfl_xor(nrm, 4);
  if (q == 0) N[row] = 10.0f * nrm;

  uint4 ho, lo;
  ho.x = hb[0] | ((unsigned)hb[1] << 16); ho.y = hb[2] | ((unsigned)hb[3] << 16);
  ho.z = hb[4] | ((unsigned)hb[5] << 16); ho.w = hb[6] | ((unsigned)hb[7] << 16);
  lo.x = lb[0] | ((unsigned)lb[1] << 16); lo.y = lb[2] | ((unsigned)lb[3] << 16);
  lo.z = lb[4] | ((unsigned)lb[5] << 16); lo.w = lb[6] | ((unsigned)lb[7] << 16);
  *(uint4*)(H + (size_t)row * DD + q * 8) = ho;
  *(uint4*)(L + (size_t)row * DD + q * 8) = lo;
}

// ---------------------------------------------------------------------------
// u_half: partial (M,S) of lse_j over reduce-chunk rc for 32 outputs (x side).
// score = bias_j + 20<y_j, x_i>; bias_j = b_j - nys_j = LOG_MU - lse_v(j)
// (merged inline from v partials; -nys at it==0). Two-sweep (validated
// r10 structure), 3 independent acc chains, grid 1024 = 16n x 32ot x 2rc.
// done derived from errBlk parity (it-1).
// ---------------------------------------------------------------------------
__global__ __launch_bounds__(256) void u_half(
    const unsigned short* __restrict__ Ahp, const unsigned short* __restrict__ Alp, // y
    const unsigned short* __restrict__ Bhp, const unsigned short* __restrict__ Blp, // x
    const float* __restrict__ nA,                                   // nys (it==0)
    const float* __restrict__ pmIn, const float* __restrict__ psIn, // v partials
    float* __restrict__ pmOut, float* __restrict__ psOut,           // u partials
    const float* __restrict__ errBlk, int it)
{
  const int tid = threadIdx.x;
  if (it > 0) {
    const float* eb = errBlk + ((it - 1) & 1) * NB;
    float tot = 0.f;
    #pragma unroll
    for (int k = 0; k < NB; ++k) tot += eb[k];
    if (tot * (EPSV / (float)NB) < THRESHV) return;   // frozen
  }
  const int n     = blockIdx.x >> 6;
  const int rem   = blockIdx.x & 63;
  const int otile = rem >> 1;
  const int rc    = rem & 1;
  const int l     = tid & 63;
  const int w     = tid >> 6;

  __shared__ float bias[PP];
  __shared__ float mred[4][32];
  __shared__ float sred[4][32];

  {
    const int e0 = tid * 4;
    if (it == 0) {
      float4 nv = *(const float4*)(nA + n * PP + e0);
      bias[e0+0] = -nv.x; bias[e0+1] = -nv.y; bias[e0+2] = -nv.z; bias[e0+3] = -nv.w;
    } else {
      float4 m0 = *(const float4*)(pmIn + 0 * CH + n * PP + e0);
      float4 m1 = *(const float4*)(pmIn + 1 * CH + n * PP + e0);
      float4 s0 = *(const float4*)(psIn + 0 * CH + n * PP + e0);
      float4 s1 = *(const float4*)(psIn + 1 * CH + n * PP + e0);
      float mm, ss;
      mm = fmaxf(m0.x, m1.x);
      ss = s0.x * exp2f((m0.x - mm) * LOG2E) + s1.x * exp2f((m1.x - mm) * LOG2E);
      bias[e0+0] = LOG_MU - (mm + logf(ss));
      mm = fmaxf(m0.y, m1.y);
      ss = s0.y * exp2f((m0.y - mm) * LOG2E) + s1.y * exp2f((m1.y - mm) * LOG2E);
      bias[e0+1] = LOG_MU - (mm + logf(ss));
      mm = fmaxf(m0.z, m1.z);
      ss = s0.z * exp2f((m0.z - mm) * LOG2E) + s1.z * exp2f((m1.z - mm) * LOG2E);
      bias[e0+2] = LOG_MU - (mm + logf(ss));
      mm = fmaxf(m0.w, m1.w);
      ss = s0.w * exp2f((m0.w - mm) * LOG2E) + s1.w * exp2f((m1.w - mm) * LOG2E);
      bias[e0+3] = LOG_MU - (mm + logf(ss));
    }
  }
  __syncthreads();

  const size_t brow = ((size_t)(n * PP + otile * 32 + (l & 31))) * DD;
  const int ko = 8 * (l >> 5);
  bf16x8 Bh[4], Bl[4];
  #pragma unroll
  for (int q = 0; q < 4; ++q) {
    Bh[q] = *(const bf16x8*)(Bhp + brow + q * 16 + ko);
    Bl[q] = *(const bf16x8*)(Blp + brow + q * 16 + ko);
  }

  // ---- sweep 1: max over this block's 512-row chunk (128 rows/wave) ----
  float M = -INFINITY;
  for (int jt = 0; jt < 4; ++jt) {
    const int jrow0 = rc * 512 + w * 128 + jt * 32;
    const size_t arow = ((size_t)(n * PP + jrow0 + (l & 31))) * DD;
    f32x16 a0, a1, a2;
    #pragma unroll
    for (int z = 0; z < 16; ++z) { a0[z] = 0.f; a1[z] = 0.f; a2[z] = 0.f; }
    #pragma unroll
    for (int q = 0; q < 4; ++q) {
      bf16x8 Ah = *(const bf16x8*)(Ahp + arow + q * 16 + ko);
      bf16x8 Al = *(const bf16x8*)(Alp + arow + q * 16 + ko);
      a0 = __builtin_amdgcn_mfma_f32_32x32x16_bf16(Ah, Bh[q], a0, 0, 0, 0);
      a1 = __builtin_amdgcn_mfma_f32_32x32x16_bf16(Ah, Bl[q], a1, 0, 0, 0);
      a2 = __builtin_amdgcn_mfma_f32_32x32x16_bf16(Al, Bh[q], a2, 0, 0, 0);
    }
    const int jb = jrow0 + 4 * (l >> 5);
    #pragma unroll
    for (int r = 0; r < 16; ++r)
      M = fmaxf(M, fmaf(SCALE_G, a0[r] + a1[r] + a2[r], bias[jb + (r & 3) + 8 * (r >> 2)]));
  }
  M = fmaxf(M, __shfl_xor(M, 32));
  if (l < 32) mred[w][l] = M;
  __syncthreads();
  const int c = l & 31;
  const float Mf = fmaxf(fmaxf(mred[0][c], mred[1][c]), fmaxf(mred[2][c], mred[3][c]));

  // ---- sweep 2: exp-sum vs fixed Mf ----
  float S = 0.f;
  for (int jt = 0; jt < 4; ++jt) {
    const int jrow0 = rc * 512 + w * 128 + jt * 32;
    const size_t arow = ((size_t)(n * PP + jrow0 + (l & 31))) * DD;
    f32x16 a0, a1, a2;
    #pragma unroll
    for (int z = 0; z < 16; ++z) { a0[z] = 0.f; a1[z] = 0.f; a2[z] = 0.f; }
    #pragma unroll
    for (int q = 0; q < 4; ++q) {
      bf16x8 Ah = *(const bf16x8*)(Ahp + arow + q * 16 + ko);
      bf16x8 Al = *(const bf16x8*)(Alp + arow + q * 16 + ko);
      a0 = __builtin_amdgcn_mfma_f32_32x32x16_bf16(Ah, Bh[q], a0, 0, 0, 0);
      a1 = __builtin_amdgcn_mfma_f32_32x32x16_bf16(Ah, Bl[q], a1, 0, 0, 0);
      a2 = __builtin_amdgcn_mfma_f32_32x32x16_bf16(Al, Bh[q], a2, 0, 0, 0);
    }
    const int jb = jrow0 + 4 * (l >> 5);
    #pragma unroll
    for (int r = 0; r < 16; ++r)
      S += exp2f((fmaf(SCALE_G, a0[r] + a1[r] + a2[r], bias[jb + (r & 3) + 8 * (r >> 2)]) - Mf) * LOG2E);
  }
  S += __shfl_xor(S, 32);
  if (l < 32) sred[w][l] = S;
  __syncthreads();

  if (tid < 32) {
    float Sf = sred[0][tid] + sred[1][tid] + sred[2][tid] + sred[3][tid];
    float Mc = fmaxf(fmaxf(mred[0][tid], mred[1][tid]), fmaxf(mred[2][tid], mred[3][tid]));
    const int gi = n * PP + otile * 32 + tid;
    pmOut[rc * CH + gi] = Mc;
    psOut[rc * CH + gi] = Sf;
  }
}

// ---------------------------------------------------------------------------
// v_half: mirror (A=x reduce, B=y out). Extra duties: designated blocks
// (rem==0, one per batch) compute err vs atPrev -> errBlk[it&1][n];
// when frozen, copy errBlk parity forward.
// ---------------------------------------------------------------------------
__global__ __launch_bounds__(256) void v_half(
    const unsigned short* __restrict__ Ahp, const unsigned short* __restrict__ Alp, // x
    const unsigned short* __restrict__ Bhp, const unsigned short* __restrict__ Blp, // y
    const float* __restrict__ nxs,                                  // err at it==0
    const float* __restrict__ pmIn, const float* __restrict__ psIn, // u partials
    float* __restrict__ pmOut, float* __restrict__ psOut,           // v partials
    float* __restrict__ atPrev, float* __restrict__ errBlk, int it)
{
  const int tid = threadIdx.x;
  const int n   = blockIdx.x >> 6;
  const int rem = blockIdx.x & 63;
  if (it > 0) {
    const float* eb = errBlk + ((it - 1) & 1) * NB;
    float tot = 0.f;
    #pragma unroll
    for (int k = 0; k < NB; ++k) tot += eb[k];
    if (tot * (EPSV / (float)NB) < THRESHV) {
      if (rem == 0 && tid == 0)
        errBlk[(it & 1) * NB + n] = errBlk[((it - 1) & 1) * NB + n];  // stays done
      return;
    }
  }
  const int otile = rem >> 1;
  const int rc    = rem & 1;
  const int l     = tid & 63;
  const int w     = tid >> 6;

  __shared__ float bias[PP];
  __shared__ float mred[4][32];
  __shared__ float sred[4][32];
  __shared__ float red4[4];

  float dsumT = 0.f;
  {
    const int e0 = tid * 4;
    float4 m0 = *(const float4*)(pmIn + 0 * CH + n * PP + e0);
    float4 m1 = *(const float4*)(pmIn + 1 * CH + n * PP + e0);
    float4 s0 = *(const float4*)(psIn + 0 * CH + n * PP + e0);
    float4 s1 = *(const float4*)(psIn + 1 * CH + n * PP + e0);
    float at4[4];
    float mm, ss;
    mm = fmaxf(m0.x, m1.x);
    ss = s0.x * exp2f((m0.x - mm) * LOG2E) + s1.x * exp2f((m1.x - mm) * LOG2E);
    at4[0] = LOG_MU - (mm + logf(ss));
    mm = fmaxf(m0.y, m1.y);
    ss = s0.y * exp2f((m0.y - mm) * LOG2E) + s1.y * exp2f((m1.y - mm) * LOG2E);
    at4[1] = LOG_MU - (mm + logf(ss));
    mm = fmaxf(m0.z, m1.z);
    ss = s0.z * exp2f((m0.z - mm) * LOG2E) + s1.z * exp2f((m1.z - mm) * LOG2E);
    at4[2] = LOG_MU - (mm + logf(ss));
    mm = fmaxf(m0.w, m1.w);
    ss = s0.w * exp2f((m0.w - mm) * LOG2E) + s1.w * exp2f((m1.w - mm) * LOG2E);
    at4[3] = LOG_MU - (mm + logf(ss));
    bias[e0+0] = at4[0]; bias[e0+1] = at4[1]; bias[e0+2] = at4[2]; bias[e0+3] = at4[3];
    if (rem == 0) {   // designated: err vs previous a (at-space diffs == a-space diffs)
      if (it == 0) {
        float4 nx = *(const float4*)(nxs + n * PP + e0);
        dsumT = fabsf(at4[0] + nx.x) + fabsf(at4[1] + nx.y)
              + fabsf(at4[2] + nx.z) + fabsf(at4[3] + nx.w);
      } else {
        float4 ap = *(const float4*)(atPrev + n * PP + e0);
        dsumT = fabsf(at4[0] - ap.x) + fabsf(at4[1] - ap.y)
              + fabsf(at4[2] - ap.z) + fabsf(at4[3] - ap.w);
      }
      *(float4*)(atPrev + n * PP + e0) = make_float4(at4[0], at4[1], at4[2], at4[3]);
    }
  }
  __syncthreads();

  const size_t brow = ((size_t)(n * PP + otile * 32 + (l & 31))) * DD;
  const int ko = 8 * (l >> 5);
  bf16x8 Bh[4], Bl[4];
  #pragma unroll
  for (int q = 0; q < 4; ++q) {
    Bh[q] = *(const bf16x8*)(Bhp + brow + q * 16 + ko);
    Bl[q] = *(const bf16x8*)(Blp + brow + q * 16 + ko);
  }

  float M = -INFINITY;
  for (int jt = 0; jt < 4; ++jt) {
    const int jrow0 = rc * 512 + w * 128 + jt * 32;
    const size_t arow = ((size_t)(n * PP + jrow0 + (l & 31))) * DD;
    f32x16 a0, a1, a2;
    #pragma unroll
    for (int z = 0; z < 16; ++z) { a0[z] = 0.f; a1[z] = 0.f; a2[z] = 0.f; }
    #pragma unroll
    for (int q = 0; q < 4; ++q) {
      bf16x8 Ah = *(const bf16x8*)(Ahp + arow + q * 16 + ko);
      bf16x8 Al = *(const bf16x8*)(Alp + arow + q * 16 + ko);
      a0 = __builtin_amdgcn_mfma_f32_32x32x16_bf16(Ah, Bh[q], a0, 0, 0, 0);
      a1 = __builtin_amdgcn_mfma_f32_32x32x16_bf16(Ah, Bl[q], a1, 0, 0, 0);
      a2 = __builtin_amdgcn_mfma_f32_32x32x16_bf16(Al, Bh[q], a2, 0, 0, 0);
    }
    const int jb = jrow0 + 4 * (l >> 5);
    #pragma unroll
    for (int r = 0; r < 16; ++r)
      M = fmaxf(M, fmaf(SCALE_G, a0[r] + a1[r] + a2[r], bias[jb + (r & 3) + 8 * (r >> 2)]));
  }
  M = fmaxf(M, __shfl_xor(M, 32));
  if (l < 32) mred[w][l] = M;
  __syncthreads();
  const int c = l & 31;
  const float Mf = fmaxf(fmaxf(mred[0][c], mred[1][c]), fmaxf(mred[2][c], mred[3][c]));

  float S = 0.f;
  for (int jt = 0; jt < 4; ++jt) {
    const int jrow0 = rc * 512 + w * 128 + jt * 32;
    const size_t arow = ((size_t)(n * PP + jrow0 + (l & 31))) * DD;
    f32x16 a0, a1, a2;
    #pragma unroll
    for (int z = 0; z < 16; ++z) { a0[z] = 0.f; a1[z] = 0.f; a2[z] = 0.f; }
    #pragma unroll
    for (int q = 0; q < 4; ++q) {
      bf16x8 Ah = *(const bf16x8*)(Ahp + arow + q * 16 + ko);
      bf16x8 Al = *(const bf16x8*)(Alp + arow + q * 16 + ko);
      a0 = __builtin_amdgcn_mfma_f32_32x32x16_bf16(Ah, Bh[q], a0, 0, 0, 0);
      a1 = __builtin_amdgcn_mfma_f32_32x32x16_bf16(Ah, Bl[q], a1, 0, 0, 0);
      a2 = __builtin_amdgcn_mfma_f32_32x32x16_bf16(Al, Bh[q], a2, 0, 0, 0);
    }
    const int jb = jrow0 + 4 * (l >> 5);
    #pragma unroll
    for (int r = 0; r < 16; ++r)
      S += exp2f((fmaf(SCALE_G, a0[r] + a1[r] + a2[r], bias[jb + (r & 3) + 8 * (r >> 2)]) - Mf) * LOG2E);
  }
  S += __shfl_xor(S, 32);
  if (l < 32) sred[w][l] = S;
  __syncthreads();

  if (tid < 32) {
    float Sf = sred[0][tid] + sred[1][tid] + sred[2][tid] + sred[3][tid];
    float Mc = fmaxf(fmaxf(mred[0][tid], mred[1][tid]), fmaxf(mred[2][tid], mred[3][tid]));
    const int gi = n * PP + otile * 32 + tid;
    pmOut[rc * CH + gi] = Mc;
    psOut[rc * CH + gi] = Sf;
  }

  // designated: fixed-order err reduce -> errBlk[it&1][n]
  if (rem == 0) {
    #pragma unroll
    for (int off = 32; off; off >>= 1) dsumT += __shfl_xor(dsumT, off);
    if (l == 0) red4[w] = dsumT;
  }
  __syncthreads();
  if (rem == 0 && tid == 0)
    errBlk[(it & 1) * NB + n] = red4[0] + red4[1] + red4[2] + red4[3];
}

// ---------------------------------------------------------------------------
// Materialize final duals from partials (for the validated epilogue).
// ---------------------------------------------------------------------------
__global__ __launch_bounds__(256) void finalize_duals(
    const float* __restrict__ pmU, const float* __restrict__ psU,
    const float* __restrict__ pmV, const float* __restrict__ psV,
    const float* __restrict__ nxs, const float* __restrict__ nys,
    float* __restrict__ aG, float* __restrict__ bG)
{
  const int gi = blockIdx.x * 256 + threadIdx.x;   // 0..16383
  float m0 = pmU[gi], m1 = pmU[CH + gi];
  float s0 = psU[gi], s1 = psU[CH + gi];
  float mm = fmaxf(m0, m1);
  float ss = s0 * exp2f((m0 - mm) * LOG2E) + s1 * exp2f((m1 - mm) * LOG2E);
  aG[gi] = LOG_MU + nxs[gi] - (mm + logf(ss));
  m0 = pmV[gi]; m1 = pmV[CH + gi];
  s0 = psV[gi]; s1 = psV[CH + gi];
  mm = fmaxf(m0, m1);
  ss = s0 * exp2f((m0 - mm) * LOG2E) + s1 * exp2f((m1 - mm) * LOG2E);
  bG[gi] = LOG_MU + nys[gi] - (mm + logf(ss));
}

// ---------------------------------------------------------------------------
// Cs = nxs_i + nys_j - 20*<x_i,y_j> via split-bf16 MFMA (validated r8).
// ---------------------------------------------------------------------------
__global__ __launch_bounds__(256) void compute_c_mfma(
    const unsigned short* __restrict__ xh, const unsigned short* __restrict__ xl,
    const float* __restrict__ nxs,
    const unsigned short* __restrict__ yh, const unsigned short* __restrict__ yl,
    const float* __restrict__ nys,
    float* __restrict__ Cs)
{
  const int n   = blockIdx.x >> 8;
  const int ib  = (blockIdx.x >> 4) & 15;
  const int jb  = blockIdx.x & 15;
  const int tid = threadIdx.x;
  const int l   = tid & 63;
  const int w   = tid >> 6;
  const int ih  = w & 1, jh = w >> 1;

  __shared__ float nxv[64];
  if (tid < 64) nxv[tid] = nxs[n * PP + ib * 64 + tid];
  __syncthreads();

  const int jg  = n * PP + jb * 64 + 32 * jh + (l & 31);
  const float nyv = nys[jg];

  const int ko = 8 * (l >> 5);
  const size_t xrow = ((size_t)(n * PP + ib * 64 + 32 * ih + (l & 31))) * DD;
  const size_t yrow = ((size_t)jg) * DD;

  bf16x8 Xh0 = *(const bf16x8*)(xh + xrow + 0 * 16 + ko);
  bf16x8 Xh1 = *(const bf16x8*)(xh + xrow + 1 * 16 + ko);
  bf16x8 Xh2 = *(const bf16x8*)(xh + xrow + 2 * 16 + ko);
  bf16x8 Xh3 = *(const bf16x8*)(xh + xrow + 3 * 16 + ko);
  bf16x8 Xl0 = *(const bf16x8*)(xl + xrow + 0 * 16 + ko);
  bf16x8 Xl1 = *(const bf16x8*)(xl + xrow + 1 * 16 + ko);
  bf16x8 Xl2 = *(const bf16x8*)(xl + xrow + 2 * 16 + ko);
  bf16x8 Xl3 = *(const bf16x8*)(xl + xrow + 3 * 16 + ko);
  bf16x8 Yh0 = *(const bf16x8*)(yh + yrow + 0 * 16 + ko);
  bf16x8 Yh1 = *(const bf16x8*)(yh + yrow + 1 * 16 + ko);
  bf16x8 Yh2 = *(const bf16x8*)(yh + yrow + 2 * 16 + ko);
  bf16x8 Yh3 = *(const bf16x8*)(yh + yrow + 3 * 16 + ko);
  bf16x8 Yl0 = *(const bf16x8*)(yl + yrow + 0 * 16 + ko);
  bf16x8 Yl1 = *(const bf16x8*)(yl + yrow + 1 * 16 + ko);
  bf16x8 Yl2 = *(const bf16x8*)(yl + yrow + 2 * 16 + ko);
  bf16x8 Yl3 = *(const bf16x8*)(yl + yrow + 3 * 16 + ko);

  f32x16 acc;
  #pragma unroll
  for (int z = 0; z < 16; ++z) acc[z] = 0.f;
  acc = __builtin_amdgcn_mfma_f32_32x32x16_bf16(Xh0, Yh0, acc, 0, 0, 0);
  acc = __builtin_amdgcn_mfma_f32_32x32x16_bf16(Xh1, Yh1, acc, 0, 0, 0);
  acc = __builtin_amdgcn_mfma_f32_32x32x16_bf16(Xh2, Yh2, acc, 0, 0, 0);
  acc = __builtin_amdgcn_mfma_f32_32x32x16_bf16(Xh3, Yh3, acc, 0, 0, 0);
  acc = __builtin_amdgcn_mfma_f32_32x32x16_bf16(Xh0, Yl0, acc, 0, 0, 0);
  acc = __builtin_amdgcn_mfma_f32_32x32x16_bf16(Xh1, Yl1, acc, 0, 0, 0);
  acc = __builtin_amdgcn_mfma_f32_32x32x16_bf16(Xh2, Yl2, acc, 0, 0, 0);
  acc = __builtin_amdgcn_mfma_f32_32x32x16_bf16(Xh3, Yl3, acc, 0, 0, 0);
  acc = __builtin_amdgcn_mfma_f32_32x32x16_bf16(Xl0, Yh0, acc, 0, 0, 0);
  acc = __builtin_amdgcn_mfma_f32_32x32x16_bf16(Xl1, Yh1, acc, 0, 0, 0);
  acc = __builtin_amdgcn_mfma_f32_32x32x16_bf16(Xl2, Yh2, acc, 0, 0, 0);
  acc = __builtin_amdgcn_mfma_f32_32x32x16_bf16(Xl3, Yh3, acc, 0, 0, 0);

  const int irb  = 32 * ih + 4 * (l >> 5);
  const int jcol = jb * 64 + 32 * jh + (l & 31);
  #pragma unroll
  for (int r = 0; r < 16; ++r) {
    const int irel = irb + (r & 3) + 8 * (r >> 2);
    const size_t off = ((size_t)(n * PP + ib * 64 + irel)) * PP + jcol;
    Cs[off] = nxv[irel] + nyv - SCALE_G * acc[r];
  }
}

// ---------------------------------------------------------------------------
// pi = exp(a_i + b_j - Cs_ij), in place over Cs (d_out). (validated)
// ---------------------------------------------------------------------------
__global__ __launch_bounds__(256) void pi_kernel(
    float* __restrict__ Cs, const float* __restrict__ a, const float* __restrict__ b)
{
  const int lane = threadIdx.x & 63;
  const int row  = (blockIdx.x << 2) + (threadIdx.x >> 6);
  const int n    = row >> 10;
  const float ai = a[row];
  float* crow = Cs + (size_t)row * PP;
  const float* bn = b + n * PP;
  #pragma unroll
  for (int kk = 0; kk < 4; ++kk) {
    float4 c4 = *(const float4*)(crow + lane * 4 + kk * 256);
    float4 b4 = *(const float4*)(bn   + lane * 4 + kk * 256);
    float4 r;
    r.x = exp2f((ai + b4.x - c4.x) * LOG2E);
    r.y = exp2f((ai + b4.y - c4.y) * LOG2E);
    r.z = exp2f((ai + b4.z - c4.z) * LOG2E);
    r.w = exp2f((ai + b4.w - c4.w) * LOG2E);
    *(float4*)(crow + lane * 4 + kk * 256) = r;
  }
}

extern "C" void kernel_launch(void* const* d_in, const int* in_sizes, int n_in,
                              void* d_out, int out_size, void* d_ws, size_t ws_size,
                              hipStream_t stream)
{
  const float* y = (const float*)d_in[0];   // setup_inputs order: y first
  const float* x = (const float*)d_in[1];

  float* Cs = (float*)d_out;                 // Cs (epilogue only), then pi in place

  const size_t NE = (size_t)NB * PP * DD;    // 1,048,576 elems per split array
  unsigned short* xh = (unsigned short*)d_ws;
  unsigned short* xl = xh + NE;
  unsigned short* yh = xl + NE;
  unsigned short* yl = yh + NE;
  float* nxs    = (float*)(yl + NE);         // 16K floats
  float* nys    = nxs + CH;                  // 16K
  float* pmU    = nys + CH;                  // 2*CH = 32K
  float* psU    = pmU + 2 * CH;              // 32K
  float* pmV    = psU + 2 * CH;              // 32K
  float* psV    = pmV + 2 * CH;              // 32K
  float* atPrev = psV + 2 * CH;              // 16K
  float* aG     = atPrev + CH;               // 16K
  float* bG     = aG + CH;                   // 16K
  float* errBlk = bG + CH;                   // 32 floats [2][16]

  prep_kernel<<<1024, 256, 0, stream>>>(x, y, xh, xl, yh, yl, nxs, nys);
  for (int it = 0; it < MAX_ITER; ++it) {
    u_half<<<1024, 256, 0, stream>>>(yh, yl, xh, xl, nys,
                                     pmV, psV, pmU, psU, errBlk, it);
    v_half<<<1024, 256, 0, stream>>>(xh, xl, yh, yl, nxs,
                                     pmU, psU, pmV, psV, atPrev, errBlk, it);
  }
  finalize_duals<<<64, 256, 0, stream>>>(pmU, psU, pmV, psV, nxs, nys, aG, bG);
  compute_c_mfma<<<4096, 256, 0, stream>>>(xh, xl, nxs, yh, yl, nys, Cs);
  pi_kernel<<<NB * PP / 4, 256, 0, stream>>>(Cs, aG, bG);
}

// Round 13
// 496.406 us; speedup vs baseline: 1.6518x; 1.6518x over previous
//
#include <hip/hip_runtime.h>
#include <math.h>

#define NB 16
#define PP 1024
#define DD 64
#define MAX_ITER 10
#define CH (NB * PP)           // partial-chunk stride (16384)

constexpr float EPSV    = 0.1f;
constexpr float SCALE_G = 20.0f;     // 2/eps
constexpr float LOG2E   = 1.44269504088896340736f;
constexpr float LOG_MU  = -6.93146156597137f;   // log(1/1024 + 1e-8)
constexpr float THRESHV = 0.1f;

typedef short bf16x8 __attribute__((ext_vector_type(8)));
typedef float f32x16 __attribute__((ext_vector_type(16)));

__device__ __forceinline__ unsigned short f2bf(float f) {
  unsigned int u = __float_as_uint(f);
  return (unsigned short)((u + 0x7FFFu + ((u >> 16) & 1u)) >> 16);   // RNE
}
__device__ __forceinline__ float bf2f(unsigned short h) {
  return __uint_as_float(((unsigned int)h) << 16);
}

// Packed-fragment addressing: pk[((group*4 + q)*64 + lane)*8] holds the bf16x8
// that lane `lane` needs for K-slice q of 32-row group `group` (global row =
// group*32 + (lane&31), k = q*16 + 8*(lane>>5) + r). A- and B-operand layouts
// are identical, so one packing serves both roles.
__device__ __forceinline__ const bf16x8* frag(const unsigned short* pk, int g, int q, int l) {
  return (const bf16x8*)(pk + (((size_t)g * 4 + q) * 64 + l) * 8);
}

// ---------------------------------------------------------------------------
// Prep: bf16 hi/lo split into PACKED fragment layout + scaled row norms.
// Grid 1024: sel = bid>>9 (0=x,1=y); 32 rows/block; 8 threads/row (q=tid&7
// covers elements k=8q..8q+7 = fragment (qk=q>>1, half=q&1)).
// ---------------------------------------------------------------------------
__global__ __launch_bounds__(256) void prep_kernel(
    const float* __restrict__ x, const float* __restrict__ y,
    unsigned short* __restrict__ xhp, unsigned short* __restrict__ xlp,
    unsigned short* __restrict__ yhp, unsigned short* __restrict__ ylp,
    float* __restrict__ nxs, float* __restrict__ nys)
{
  const int sel = blockIdx.x >> 9;
  const int row = (blockIdx.x & 511) * 32 + (threadIdx.x >> 3);   // global 0..16383
  const int q   = threadIdx.x & 7;

  const float* src = sel ? y : x;
  unsigned short* H = sel ? yhp : xhp;
  unsigned short* L = sel ? ylp : xlp;
  float* N          = sel ? nys : nxs;

  const float* p = src + (size_t)row * DD + q * 8;
  float4 v0 = *(const float4*)(p);
  float4 v1 = *(const float4*)(p + 4);

  float f[8] = {v0.x, v0.y, v0.z, v0.w, v1.x, v1.y, v1.z, v1.w};
  float nrm = 0.f;
  unsigned short hb[8], lb[8];
  #pragma unroll
  for (int k = 0; k < 8; ++k) {
    nrm = fmaf(f[k], f[k], nrm);
    unsigned short h = f2bf(f[k]);
    float res = f[k] - bf2f(h);
    hb[k] = h; lb[k] = f2bf(res);
  }
  nrm += __shfl_xor(nrm, 1);
  nrm += __shfl_xor(nrm, 2);
  nrm += __shfl_xor(nrm, 4);
  if (q == 0) N[row] = 10.0f * nrm;

  uint4 ho, lo;
  ho.x = hb[0] | ((unsigned)hb[1] << 16); ho.y = hb[2] | ((unsigned)hb[3] << 16);
  ho.z = hb[4] | ((unsigned)hb[5] << 16); ho.w = hb[6] | ((unsigned)hb[7] << 16);
  lo.x = lb[0] | ((unsigned)lb[1] << 16); lo.y = lb[2] | ((unsigned)lb[3] << 16);
  lo.z = lb[4] | ((unsigned)lb[5] << 16); lo.w = lb[6] | ((unsigned)lb[7] << 16);

  const int grp  = row >> 5;
  const int lane = (row & 31) + 32 * (q & 1);
  const size_t dst = (((size_t)grp * 4 + (q >> 1)) * 64 + lane) * 8;
  *(uint4*)(H + dst) = ho;
  *(uint4*)(L + dst) = lo;
}

// ---------------------------------------------------------------------------
// u_half: partial (M,S) of lse_j over reduce-chunk rc for 32 outputs (x side).
// bias_j = b_j - nys_j merged inline from v partials (-nys at it==0).
// Two-sweep: sweep1 max with hh-only scores (error <~1, harmless since sweep2
// uses exact scores vs that fixed Mf); sweep2 full hh+hl+lh exp-sum.
// Grid 1024, XCD-aware decode: n = bid&15 (all blocks of a batch share an XCD).
// ---------------------------------------------------------------------------
__global__ __launch_bounds__(256, 4) void u_half(
    const unsigned short* __restrict__ Ahp, const unsigned short* __restrict__ Alp, // y packed
    const unsigned short* __restrict__ Bhp, const unsigned short* __restrict__ Blp, // x packed
    const float* __restrict__ nA,                                   // nys (it==0)
    const float* __restrict__ pmIn, const float* __restrict__ psIn, // v partials
    float* __restrict__ pmOut, float* __restrict__ psOut,           // u partials
    const float* __restrict__ errBlk, int it)
{
  const int tid = threadIdx.x;
  if (it > 0) {
    const float* eb = errBlk + ((it - 1) & 1) * NB;
    float tot = 0.f;
    #pragma unroll
    for (int k = 0; k < NB; ++k) tot += eb[k];
    if (tot * (EPSV / (float)NB) < THRESHV) return;   // frozen
  }
  const int n     = blockIdx.x & 15;
  const int rem   = blockIdx.x >> 4;
  const int otile = rem >> 1;
  const int rc    = rem & 1;
  const int l     = tid & 63;
  const int w     = tid >> 6;

  __shared__ float bias[PP];
  __shared__ float mred[4][32];
  __shared__ float sred[4][32];

  {
    const int e0 = tid * 4;
    if (it == 0) {
      float4 nv = *(const float4*)(nA + n * PP + e0);
      bias[e0+0] = -nv.x; bias[e0+1] = -nv.y; bias[e0+2] = -nv.z; bias[e0+3] = -nv.w;
    } else {
      float4 m0 = *(const float4*)(pmIn + 0 * CH + n * PP + e0);
      float4 m1 = *(const float4*)(pmIn + 1 * CH + n * PP + e0);
      float4 s0 = *(const float4*)(psIn + 0 * CH + n * PP + e0);
      float4 s1 = *(const float4*)(psIn + 1 * CH + n * PP + e0);
      float mm, ss;
      mm = fmaxf(m0.x, m1.x);
      ss = s0.x * exp2f((m0.x - mm) * LOG2E) + s1.x * exp2f((m1.x - mm) * LOG2E);
      bias[e0+0] = LOG_MU - (mm + logf(ss));
      mm = fmaxf(m0.y, m1.y);
      ss = s0.y * exp2f((m0.y - mm) * LOG2E) + s1.y * exp2f((m1.y - mm) * LOG2E);
      bias[e0+1] = LOG_MU - (mm + logf(ss));
      mm = fmaxf(m0.z, m1.z);
      ss = s0.z * exp2f((m0.z - mm) * LOG2E) + s1.z * exp2f((m1.z - mm) * LOG2E);
      bias[e0+2] = LOG_MU - (mm + logf(ss));
      mm = fmaxf(m0.w, m1.w);
      ss = s0.w * exp2f((m0.w - mm) * LOG2E) + s1.w * exp2f((m1.w - mm) * LOG2E);
      bias[e0+3] = LOG_MU - (mm + logf(ss));
    }
  }
  __syncthreads();

  const int gB = n * 32 + otile;
  bf16x8 Bh[4], Bl[4];
  #pragma unroll
  for (int q = 0; q < 4; ++q) {
    Bh[q] = *frag(Bhp, gB, q, l);
    Bl[q] = *frag(Blp, gB, q, l);
  }

  // ---- sweep 1: hh-only max over this block's 512-row chunk ----
  float M = -INFINITY;
  #pragma unroll
  for (int jt = 0; jt < 4; ++jt) {
    const int gl = rc * 16 + w * 4 + jt;       // group-in-batch (row/32)
    const int gA = n * 32 + gl;
    f32x16 a0;
    #pragma unroll
    for (int z = 0; z < 16; ++z) a0[z] = 0.f;
    #pragma unroll
    for (int q = 0; q < 4; ++q)
      a0 = __builtin_amdgcn_mfma_f32_32x32x16_bf16(*frag(Ahp, gA, q, l), Bh[q], a0, 0, 0, 0);
    const int jb = gl * 32 + 4 * (l >> 5);
    #pragma unroll
    for (int r = 0; r < 16; ++r)
      M = fmaxf(M, fmaf(SCALE_G, a0[r], bias[jb + (r & 3) + 8 * (r >> 2)]));
  }
  M = fmaxf(M, __shfl_xor(M, 32));
  if (l < 32) mred[w][l] = M;
  __syncthreads();
  const int c = l & 31;
  const float Mf = fmaxf(fmaxf(mred[0][c], mred[1][c]), fmaxf(mred[2][c], mred[3][c]));

  // ---- sweep 2: exact (hh+hl+lh) exp-sum vs fixed Mf ----
  float S = 0.f;
  #pragma unroll
  for (int jt = 0; jt < 4; ++jt) {
    const int gl = rc * 16 + w * 4 + jt;
    const int gA = n * 32 + gl;
    f32x16 a0, a1, a2;
    #pragma unroll
    for (int z = 0; z < 16; ++z) { a0[z] = 0.f; a1[z] = 0.f; a2[z] = 0.f; }
    #pragma unroll
    for (int q = 0; q < 4; ++q) {
      bf16x8 Ah = *frag(Ahp, gA, q, l);
      bf16x8 Al = *frag(Alp, gA, q, l);
      a0 = __builtin_amdgcn_mfma_f32_32x32x16_bf16(Ah, Bh[q], a0, 0, 0, 0);
      a1 = __builtin_amdgcn_mfma_f32_32x32x16_bf16(Ah, Bl[q], a1, 0, 0, 0);
      a2 = __builtin_amdgcn_mfma_f32_32x32x16_bf16(Al, Bh[q], a2, 0, 0, 0);
    }
    const int jb = gl * 32 + 4 * (l >> 5);
    #pragma unroll
    for (int r = 0; r < 16; ++r)
      S += exp2f((fmaf(SCALE_G, a0[r] + a1[r] + a2[r], bias[jb + (r & 3) + 8 * (r >> 2)]) - Mf) * LOG2E);
  }
  S += __shfl_xor(S, 32);
  if (l < 32) sred[w][l] = S;
  __syncthreads();

  if (tid < 32) {
    float Sf = sred[0][tid] + sred[1][tid] + sred[2][tid] + sred[3][tid];
    float Mc = fmaxf(fmaxf(mred[0][tid], mred[1][tid]), fmaxf(mred[2][tid], mred[3][tid]));
    const int gi = n * PP + otile * 32 + tid;
    pmOut[rc * CH + gi] = Mc;
    psOut[rc * CH + gi] = Sf;
  }
}

// ---------------------------------------------------------------------------
// v_half: mirror (A=x reduce, B=y out). Designated blocks (rem==0, one per
// batch) compute err vs atPrev -> errBlk[it&1][n]; frozen: copy parity fwd.
// ---------------------------------------------------------------------------
__global__ __launch_bounds__(256, 4) void v_half(
    const unsigned short* __restrict__ Ahp, const unsigned short* __restrict__ Alp, // x packed
    const unsigned short* __restrict__ Bhp, const unsigned short* __restrict__ Blp, // y packed
    const float* __restrict__ nxs,                                  // err at it==0
    const float* __restrict__ pmIn, const float* __restrict__ psIn, // u partials
    float* __restrict__ pmOut, float* __restrict__ psOut,           // v partials
    float* __restrict__ atPrev, float* __restrict__ errBlk, int it)
{
  const int tid = threadIdx.x;
  const int n   = blockIdx.x & 15;
  const int rem = blockIdx.x >> 4;
  if (it > 0) {
    const float* eb = errBlk + ((it - 1) & 1) * NB;
    float tot = 0.f;
    #pragma unroll
    for (int k = 0; k < NB; ++k) tot += eb[k];
    if (tot * (EPSV / (float)NB) < THRESHV) {
      if (rem == 0 && tid == 0)
        errBlk[(it & 1) * NB + n] = errBlk[((it - 1) & 1) * NB + n];
      return;
    }
  }
  const int otile = rem >> 1;
  const int rc    = rem & 1;
  const int l     = tid & 63;
  const int w     = tid >> 6;

  __shared__ float bias[PP];
  __shared__ float mred[4][32];
  __shared__ float sred[4][32];
  __shared__ float red4[4];

  float dsumT = 0.f;
  {
    const int e0 = tid * 4;
    float4 m0 = *(const float4*)(pmIn + 0 * CH + n * PP + e0);
    float4 m1 = *(const float4*)(pmIn + 1 * CH + n * PP + e0);
    float4 s0 = *(const float4*)(psIn + 0 * CH + n * PP + e0);
    float4 s1 = *(const float4*)(psIn + 1 * CH + n * PP + e0);
    float at4[4];
    float mm, ss;
    mm = fmaxf(m0.x, m1.x);
    ss = s0.x * exp2f((m0.x - mm) * LOG2E) + s1.x * exp2f((m1.x - mm) * LOG2E);
    at4[0] = LOG_MU - (mm + logf(ss));
    mm = fmaxf(m0.y, m1.y);
    ss = s0.y * exp2f((m0.y - mm) * LOG2E) + s1.y * exp2f((m1.y - mm) * LOG2E);
    at4[1] = LOG_MU - (mm + logf(ss));
    mm = fmaxf(m0.z, m1.z);
    ss = s0.z * exp2f((m0.z - mm) * LOG2E) + s1.z * exp2f((m1.z - mm) * LOG2E);
    at4[2] = LOG_MU - (mm + logf(ss));
    mm = fmaxf(m0.w, m1.w);
    ss = s0.w * exp2f((m0.w - mm) * LOG2E) + s1.w * exp2f((m1.w - mm) * LOG2E);
    at4[3] = LOG_MU - (mm + logf(ss));
    bias[e0+0] = at4[0]; bias[e0+1] = at4[1]; bias[e0+2] = at4[2]; bias[e0+3] = at4[3];
    if (rem == 0) {
      if (it == 0) {
        float4 nx = *(const float4*)(nxs + n * PP + e0);
        dsumT = fabsf(at4[0] + nx.x) + fabsf(at4[1] + nx.y)
              + fabsf(at4[2] + nx.z) + fabsf(at4[3] + nx.w);
      } else {
        float4 ap = *(const float4*)(atPrev + n * PP + e0);
        dsumT = fabsf(at4[0] - ap.x) + fabsf(at4[1] - ap.y)
              + fabsf(at4[2] - ap.z) + fabsf(at4[3] - ap.w);
      }
      *(float4*)(atPrev + n * PP + e0) = make_float4(at4[0], at4[1], at4[2], at4[3]);
    }
  }
  __syncthreads();

  const int gB = n * 32 + otile;
  bf16x8 Bh[4], Bl[4];
  #pragma unroll
  for (int q = 0; q < 4; ++q) {
    Bh[q] = *frag(Bhp, gB, q, l);
    Bl[q] = *frag(Blp, gB, q, l);
  }

  float M = -INFINITY;
  #pragma unroll
  for (int jt = 0; jt < 4; ++jt) {
    const int gl = rc * 16 + w * 4 + jt;
    const int gA = n * 32 + gl;
    f32x16 a0;
    #pragma unroll
    for (int z = 0; z < 16; ++z) a0[z] = 0.f;
    #pragma unroll
    for (int q = 0; q < 4; ++q)
      a0 = __builtin_amdgcn_mfma_f32_32x32x16_bf16(*frag(Ahp, gA, q, l), Bh[q], a0, 0, 0, 0);
    const int jb = gl * 32 + 4 * (l >> 5);
    #pragma unroll
    for (int r = 0; r < 16; ++r)
      M = fmaxf(M, fmaf(SCALE_G, a0[r], bias[jb + (r & 3) + 8 * (r >> 2)]));
  }
  M = fmaxf(M, __shfl_xor(M, 32));
  if (l < 32) mred[w][l] = M;
  __syncthreads();
  const int c = l & 31;
  const float Mf = fmaxf(fmaxf(mred[0][c], mred[1][c]), fmaxf(mred[2][c], mred[3][c]));

  float S = 0.f;
  #pragma unroll
  for (int jt = 0; jt < 4; ++jt) {
    const int gl = rc * 16 + w * 4 + jt;
    const int gA = n * 32 + gl;
    f32x16 a0, a1, a2;
    #pragma unroll
    for (int z = 0; z < 16; ++z) { a0[z] = 0.f; a1[z] = 0.f; a2[z] = 0.f; }
    #pragma unroll
    for (int q = 0; q < 4; ++q) {
      bf16x8 Ah = *frag(Ahp, gA, q, l);
      bf16x8 Al = *frag(Alp, gA, q, l);
      a0 = __builtin_amdgcn_mfma_f32_32x32x16_bf16(Ah, Bh[q], a0, 0, 0, 0);
      a1 = __builtin_amdgcn_mfma_f32_32x32x16_bf16(Ah, Bl[q], a1, 0, 0, 0);
      a2 = __builtin_amdgcn_mfma_f32_32x32x16_bf16(Al, Bh[q], a2, 0, 0, 0);
    }
    const int jb = gl * 32 + 4 * (l >> 5);
    #pragma unroll
    for (int r = 0; r < 16; ++r)
      S += exp2f((fmaf(SCALE_G, a0[r] + a1[r] + a2[r], bias[jb + (r & 3) + 8 * (r >> 2)]) - Mf) * LOG2E);
  }
  S += __shfl_xor(S, 32);
  if (l < 32) sred[w][l] = S;
  __syncthreads();

  if (tid < 32) {
    float Sf = sred[0][tid] + sred[1][tid] + sred[2][tid] + sred[3][tid];
    float Mc = fmaxf(fmaxf(mred[0][tid], mred[1][tid]), fmaxf(mred[2][tid], mred[3][tid]));
    const int gi = n * PP + otile * 32 + tid;
    pmOut[rc * CH + gi] = Mc;
    psOut[rc * CH + gi] = Sf;
  }

  if (rem == 0) {
    #pragma unroll
    for (int off = 32; off; off >>= 1) dsumT += __shfl_xor(dsumT, off);
    if (l == 0) red4[w] = dsumT;
  }
  __syncthreads();
  if (rem == 0 && tid == 0)
    errBlk[(it & 1) * NB + n] = red4[0] + red4[1] + red4[2] + red4[3];
}

// ---------------------------------------------------------------------------
// Materialize final duals from partials (validated r12).
// ---------------------------------------------------------------------------
__global__ __launch_bounds__(256) void finalize_duals(
    const float* __restrict__ pmU, const float* __restrict__ psU,
    const float* __restrict__ pmV, const float* __restrict__ psV,
    const float* __restrict__ nxs, const float* __restrict__ nys,
    float* __restrict__ aG, float* __restrict__ bG)
{
  const int gi = blockIdx.x * 256 + threadIdx.x;   // 0..16383
  float m0 = pmU[gi], m1 = pmU[CH + gi];
  float s0 = psU[gi], s1 = psU[CH + gi];
  float mm = fmaxf(m0, m1);
  float ss = s0 * exp2f((m0 - mm) * LOG2E) + s1 * exp2f((m1 - mm) * LOG2E);
  aG[gi] = LOG_MU + nxs[gi] - (mm + logf(ss));
  m0 = pmV[gi]; m1 = pmV[CH + gi];
  s0 = psV[gi]; s1 = psV[CH + gi];
  mm = fmaxf(m0, m1);
  ss = s0 * exp2f((m0 - mm) * LOG2E) + s1 * exp2f((m1 - mm) * LOG2E);
  bG[gi] = LOG_MU + nys[gi] - (mm + logf(ss));
}

// ---------------------------------------------------------------------------
// Cs = nxs_i + nys_j - 20*<x_i,y_j> via split-bf16 MFMA (validated r8 math;
// packed-fragment loads + XCD-aware decode n = bid&15).
// ---------------------------------------------------------------------------
__global__ __launch_bounds__(256) void compute_c_mfma(
    const unsigned short* __restrict__ xhp, const unsigned short* __restrict__ xlp,
    const float* __restrict__ nxs,
    const unsigned short* __restrict__ yhp, const unsigned short* __restrict__ ylp,
    const float* __restrict__ nys,
    float* __restrict__ Cs)
{
  const int n   = blockIdx.x & 15;
  const int ib  = (blockIdx.x >> 4) & 15;
  const int jb  = blockIdx.x >> 8;
  const int tid = threadIdx.x;
  const int l   = tid & 63;
  const int w   = tid >> 6;
  const int ih  = w & 1, jh = w >> 1;

  __shared__ float nxv[64];
  if (tid < 64) nxv[tid] = nxs[n * PP + ib * 64 + tid];
  __syncthreads();

  const int jg  = n * PP + jb * 64 + 32 * jh + (l & 31);
  const float nyv = nys[jg];

  const int gX = n * 32 + ib * 2 + ih;
  const int gY = n * 32 + jb * 2 + jh;

  f32x16 acc;
  #pragma unroll
  for (int z = 0; z < 16; ++z) acc[z] = 0.f;
  #pragma unroll
  for (int q = 0; q < 4; ++q) {
    bf16x8 Xh = *frag(xhp, gX, q, l);
    bf16x8 Xl = *frag(xlp, gX, q, l);
    bf16x8 Yh = *frag(yhp, gY, q, l);
    bf16x8 Yl = *frag(ylp, gY, q, l);
    acc = __builtin_amdgcn_mfma_f32_32x32x16_bf16(Xh, Yh, acc, 0, 0, 0);
    acc = __builtin_amdgcn_mfma_f32_32x32x16_bf16(Xh, Yl, acc, 0, 0, 0);
    acc = __builtin_amdgcn_mfma_f32_32x32x16_bf16(Xl, Yh, acc, 0, 0, 0);
  }

  const int irb  = 32 * ih + 4 * (l >> 5);
  const int jcol = jb * 64 + 32 * jh + (l & 31);
  #pragma unroll
  for (int r = 0; r < 16; ++r) {
    const int irel = irb + (r & 3) + 8 * (r >> 2);
    const size_t off = ((size_t)(n * PP + ib * 64 + irel)) * PP + jcol;
    Cs[off] = nxv[irel] + nyv - SCALE_G * acc[r];
  }
}

// ---------------------------------------------------------------------------
// pi = exp(a_i + b_j - Cs_ij), in place over Cs (d_out). (validated)
// ---------------------------------------------------------------------------
__global__ __launch_bounds__(256) void pi_kernel(
    float* __restrict__ Cs, const float* __restrict__ a, const float* __restrict__ b)
{
  const int lane = threadIdx.x & 63;
  const int row  = (blockIdx.x << 2) + (threadIdx.x >> 6);
  const int n    = row >> 10;
  const float ai = a[row];
  float* crow = Cs + (size_t)row * PP;
  const float* bn = b + n * PP;
  #pragma unroll
  for (int kk = 0; kk < 4; ++kk) {
    float4 c4 = *(const float4*)(crow + lane * 4 + kk * 256);
    float4 b4 = *(const float4*)(bn   + lane * 4 + kk * 256);
    float4 r;
    r.x = exp2f((ai + b4.x - c4.x) * LOG2E);
    r.y = exp2f((ai + b4.y - c4.y) * LOG2E);
    r.z = exp2f((ai + b4.z - c4.z) * LOG2E);
    r.w = exp2f((ai + b4.w - c4.w) * LOG2E);
    *(float4*)(crow + lane * 4 + kk * 256) = r;
  }
}

extern "C" void kernel_launch(void* const* d_in, const int* in_sizes, int n_in,
                              void* d_out, int out_size, void* d_ws, size_t ws_size,
                              hipStream_t stream)
{
  const float* y = (const float*)d_in[0];   // setup_inputs order: y first
  const float* x = (const float*)d_in[1];

  float* Cs = (float*)d_out;                 // Cs (epilogue only), then pi in place

  const size_t NE = (size_t)NB * PP * DD;    // 1,048,576 elems per packed array
  unsigned short* xhp = (unsigned short*)d_ws;
  unsigned short* xlp = xhp + NE;
  unsigned short* yhp = xlp + NE;
  unsigned short* ylp = yhp + NE;
  float* nxs    = (float*)(ylp + NE);        // 16K floats
  float* nys    = nxs + CH;                  // 16K
  float* pmU    = nys + CH;                  // 2*CH
  float* psU    = pmU + 2 * CH;
  float* pmV    = psU + 2 * CH;
  float* psV    = pmV + 2 * CH;
  float* atPrev = psV + 2 * CH;              // 16K
  float* aG     = atPrev + CH;               // 16K
  float* bG     = aG + CH;                   // 16K
  float* errBlk = bG + CH;                   // 32 floats [2][16]

  prep_kernel<<<1024, 256, 0, stream>>>(x, y, xhp, xlp, yhp, ylp, nxs, nys);
  for (int it = 0; it < MAX_ITER; ++it) {
    u_half<<<1024, 256, 0, stream>>>(yhp, ylp, xhp, xlp, nys,
                                     pmV, psV, pmU, psU, errBlk, it);
    v_half<<<1024, 256, 0, stream>>>(xhp, xlp, yhp, ylp, nxs,
                                     pmU, psU, pmV, psV, atPrev, errBlk, it);
  }
  finalize_duals<<<64, 256, 0, stream>>>(pmU, psU, pmV, psV, nxs, nys, aG, bG);
  compute_c_mfma<<<4096, 256, 0, stream>>>(xhp, xlp, nxs, yhp, ylp, nys, Cs);
  pi_kernel<<<NB * PP / 4, 256, 0, stream>>>(Cs, aG, bG);
}